// Round 6
// baseline (161.762 us; speedup 1.0000x reference)
//
#include <hip/hip_runtime.h>

#define BS 32
#define NE 512
#define DMODEL 512
#define HEADS 8
#define EMB 64
#define FFH 256
#define MTOK (BS*NE)   // 16384

typedef unsigned short u16;
typedef short v8s __attribute__((ext_vector_type(8)));
typedef float f32x4 __attribute__((ext_vector_type(4)));
typedef u16 u16x4 __attribute__((ext_vector_type(4)));

#define GLOAD16(G, L) \
  __builtin_amdgcn_global_load_lds((const __attribute__((address_space(1))) unsigned int*)(G), \
      (__attribute__((address_space(3))) unsigned int*)(L), 16, 0, 0)

static __device__ __forceinline__ unsigned cvt_pk_bf16(float lo, float hi) {
    unsigned r;
    asm("v_cvt_pk_bf16_f32 %0, %1, %2" : "=v"(r) : "v"(lo), "v"(hi));
    return r;
}

static __device__ __forceinline__ u16 f2bf_bits(float f) {
    unsigned u = __float_as_uint(f);
    u += 0x7fffu + ((u >> 16) & 1u);   // round-to-nearest-even
    return (u16)(u >> 16);
}
static __device__ __forceinline__ float bf2f_bits(u16 h) {
    return __uint_as_float(((unsigned)h) << 16);
}

// ---------------- conversion kernels ----------------

__global__ __launch_bounds__(256) void cvt_x_kernel(const float* __restrict__ x,
                                                    u16* __restrict__ xb, int n4) {
    int i = blockIdx.x * 256 + threadIdx.x;
    if (i >= n4) return;
    float4 v = ((const float4*)x)[i];
    u16x4 o = { f2bf_bits(v.x), f2bf_bits(v.y), f2bf_bits(v.z), f2bf_bits(v.w) };
    ((u16x4*)xb)[i] = o;
}

// all 5 weights -> transposed bf16 in one kernel.
__global__ __launch_bounds__(256) void cvt_w_kernel(
    const float* __restrict__ Wq, const float* __restrict__ Wk, const float* __restrict__ Wv,
    const float* __restrict__ W1, const float* __restrict__ W2,
    u16* __restrict__ WqkvT, u16* __restrict__ W1T, u16* __restrict__ W2T)
{
    int idx = blockIdx.x * 256 + threadIdx.x;   // 0 .. 1048575
    if (idx < 786432) {
        int w = idx >> 18, rem = idx & 262143;
        int k = rem >> 9, n = rem & 511;
        const float* src = (w == 0) ? Wq : (w == 1) ? Wk : Wv;
        WqkvT[(size_t)(w*512 + n)*512 + k] = f2bf_bits(src[rem]);
    } else if (idx < 917504) {
        int rem = idx - 786432;        // W1: [512][256]
        int k = rem >> 8, n = rem & 255;
        W1T[n*512 + k] = f2bf_bits(W1[rem]);
    } else if (idx < 1048576) {
        int rem = idx - 917504;        // W2: [256][512]
        int k = rem >> 9, n = rem & 511;
        W2T[n*256 + k] = f2bf_bits(W2[rem]);
    }
}

// ---------------- GEMM: C = A(MxKC) @ BT(NxKC)^T + bias ----------------
// 128x128 tile, 4 waves, BK=64, double-buffered LDS, 2-phase pipeline:
// one raw s_barrier per K-step; next tile's global_load_lds issued after the
// barrier so its latency hides under the 32 MFMAs (no vmcnt(0)+lgkmcnt(0) drain).
// EPI 0: plain store   EPI 2: relu+store   EPI 3: fused QKV scatter (Q pre-scaled)
template<int EPI, int KC>
__global__ __launch_bounds__(256, 2) void gemm_kernel(
    const u16* __restrict__ A, const u16* __restrict__ BT,
    const float* __restrict__ bsQ, const float* __restrict__ bsK, const float* __restrict__ bsV,
    u16* __restrict__ oQ, u16* __restrict__ oK, u16* __restrict__ oVT,
    int N, int NC)
{
    __shared__ u16 Ab[2][128*64];
    __shared__ u16 Bb[2][128*64];
    const int tid = threadIdx.x;
    const int wave = tid >> 6, lane = tid & 63;
    const int lr = lane & 15, lg = lane >> 4, lr7 = lr & 7;
    const int id = blockIdx.x;
    const int rr = id & 7, qq = id >> 3;
    const int gk = qq / NC, colBlk = qq - gk*NC;
    const int rowBlk = gk*8 + rr;
    const int aRow0 = rowBlk*128, bRow0 = colBlk*128;
    const int wlo = (wave >> 1)*64, wco = (wave & 1)*64;
    const int srow = tid >> 3, schunk = tid & 7;
    const int soff = ((schunk ^ (srow & 7)) << 3);

    // stage one 128x64 A-tile + B-tile into buffer bsel (8 loads/thread)
    auto stage = [&](int bsel, int k0) {
        #pragma unroll
        for (int i = 0; i < 4; ++i) {
            int row = i*32 + srow;
            GLOAD16(A  + (size_t)(aRow0 + row)*KC + k0 + soff, (char*)&Ab[bsel][0] + i*4096 + wave*1024);
            GLOAD16(BT + (size_t)(bRow0 + row)*KC + k0 + soff, (char*)&Bb[bsel][0] + i*4096 + wave*1024);
        }
    };

    stage(0, 0);

    f32x4 acc[4][4] = {};
    constexpr int NT = KC / 64;
    #pragma unroll
    for (int t = 0; t < NT; ++t) {
        const int cur = t & 1;
        asm volatile("s_waitcnt vmcnt(0)" ::: "memory");   // tile t's loads landed
        __builtin_amdgcn_s_barrier();                      // all waves agree; prev reads done
        if (t + 1 < NT) stage(cur ^ 1, (t + 1) * 64);      // prefetch: hides under MFMAs
        #pragma unroll
        for (int kk = 0; kk < 2; ++kk) {
            v8s af[4], bf[4];
            #pragma unroll
            for (int i = 0; i < 4; ++i) {
                af[i] = *(const v8s*)((const char*)&Ab[cur][0] + (wlo + i*16 + lr)*128 + ((((kk<<2)|lg) ^ lr7) << 4));
                bf[i] = *(const v8s*)((const char*)&Bb[cur][0] + (wco + i*16 + lr)*128 + ((((kk<<2)|lg) ^ lr7) << 4));
            }
            #pragma unroll
            for (int i = 0; i < 4; ++i)
                #pragma unroll
                for (int j = 0; j < 4; ++j)
                    acc[i][j] = __builtin_amdgcn_mfma_f32_16x16x32_bf16(af[i], bf[j], acc[i][j], 0, 0, 0);
        }
    }

    const int sel = (EPI == 3) ? (bRow0 >> 9) : 0;
    const float* bias = (EPI == 3) ? (sel == 0 ? bsQ : (sel == 1 ? bsK : bsV)) : bsQ;
    #pragma unroll
    for (int j = 0; j < 4; ++j) {
        int colg = bRow0 + wco + j*16 + lr;
        int col = (EPI == 3) ? (colg & 511) : colg;
        float bv = bias[col];
        #pragma unroll
        for (int i = 0; i < 4; ++i) {
            #pragma unroll
            for (int r = 0; r < 4; ++r) {
                int row = aRow0 + wlo + i*16 + lg*4 + r;
                float v = acc[i][j][r] + bv;
                if (EPI == 2) v = fmaxf(v, 0.f);
                if (EPI == 3 && sel == 0) v *= 0.18033688011112042f;  // 0.125*log2(e) for exp2 softmax
                u16 hv = f2bf_bits(v);
                if (EPI == 3) {
                    if (sel == 0)      oQ[(size_t)row*DMODEL + col] = hv;
                    else if (sel == 1) oK[(size_t)row*DMODEL + col] = hv;
                    else {
                        int bb = row >> 9, t = row & 511;
                        int hh = col >> 6, d = col & 63;
                        oVT[((size_t)((bb*HEADS + hh)*EMB + d))*NE + t] = hv;
                    }
                } else {
                    oQ[(size_t)row*N + colg] = hv;
                }
            }
        }
    }
}

// ---------------- attention (streaming, swapped-operand, permuted-key PV) ----------------
// 1 block = 1 (b,h); 8 waves x 64 queries. K [512][64] swizzled + V^T [64 rows x 1040B
// padded, linear] in LDS. Per 32-key chunk: two S^T = mfma(K,Q) 16-key tiles; lane
// (q=lr, g=lg) holds P^T keys {4g..4g+3} (tile0) and {16+4g..+3} (tile1) = a 16x16x32
// B-fragment under key-permutation pi(g,j); V^T A-fragment reads the same permuted keys
// (two 8B LDS reads, +0/+32B). O accumulates as O[q=lr][d=4g+r]; normalize at end,
// transpose via LDS, coalesced 16B stores. Q pre-scaled so P = exp2(S).
__global__ __launch_bounds__(512, 2) void attn_kernel(
    const u16* __restrict__ Q, const u16* __restrict__ Kb,
    const u16* __restrict__ VT, u16* __restrict__ O)
{
    extern __shared__ char smem[];   // [0,64K) K swz; [64K, 64K+66560) V^T padded
    const int b = blockIdx.x >> 3, h = blockIdx.x & 7;
    const int tid = threadIdx.x, wave = tid >> 6, lane = tid & 63;
    const int lr = lane & 15, lg = lane >> 4, lr7 = lr & 7;

    // stage K rows (128B, 8x16B chunks, chunk ^= row&7), pre-swizzled source
    const int srow = tid >> 3, schunk = tid & 7;
    const int soff = ((schunk ^ (srow & 7)) << 3);
    #pragma unroll
    for (int i = 0; i < 8; ++i)
        GLOAD16(Kb + (size_t)(b*NE + i*64 + srow)*DMODEL + h*EMB + soff,
                (char*)smem + i*8192 + wave*1024);
    // stage V^T rows: 1024B data per row, stride 1040B, linear (no swizzle)
    #pragma unroll
    for (int i = 0; i < 8; ++i) {
        int row = i*8 + wave;
        GLOAD16(VT + (size_t)((b*HEADS + h)*EMB + row)*NE + lane*8,
                (char*)smem + 65536 + row*1040);
    }

    // Q fragments direct from global (L2-resident); Q pre-scaled by 0.125*log2e
    const int q0 = wave*64;
    v8s qa[4][2];
    #pragma unroll
    for (int ti = 0; ti < 4; ++ti) {
        const u16* qr = Q + (size_t)(b*NE + q0 + ti*16 + lr)*DMODEL + h*EMB;
        qa[ti][0] = *(const v8s*)(qr + lg*8);
        qa[ti][1] = *(const v8s*)(qr + 32 + lg*8);
    }
    __syncthreads();

    f32x4 o[4][4] = {};
    float ssum[4] = {0.f, 0.f, 0.f, 0.f};

    #pragma unroll 1
    for (int c = 0; c < 16; ++c) {
        // K A-fragments for the two 16-key tiles of this chunk
        const char* kr0 = (const char*)smem + ((2*c  )*16 + lr)*128;
        const char* kr1 = (const char*)smem + ((2*c+1)*16 + lr)*128;
        v8s kA0 = *(const v8s*)(kr0 + ((lg ^ lr7) << 4));
        v8s kA1 = *(const v8s*)(kr0 + (((4|lg) ^ lr7) << 4));
        v8s kB0 = *(const v8s*)(kr1 + ((lg ^ lr7) << 4));
        v8s kB1 = *(const v8s*)(kr1 + (((4|lg) ^ lr7) << 4));
        // V^T permuted A-fragments: lane (d=dt*16+lr, g=lg) gets keys
        // c*32 + {4g..4g+3} and c*32 + {16+4g..16+4g+3}
        v8s vf[4];
        #pragma unroll
        for (int dt = 0; dt < 4; ++dt) {
            const char* vr = (const char*)smem + 65536 + (dt*16 + lr)*1040 + c*64 + lg*8;
            uint2 lo = *(const uint2*)(vr);
            uint2 hi = *(const uint2*)(vr + 32);
            uint4 u = make_uint4(lo.x, lo.y, hi.x, hi.y);
            vf[dt] = *(v8s*)&u;
        }
        #pragma unroll
        for (int ti = 0; ti < 4; ++ti) {
            // swapped: S^T[key][q]; lane holds key=4lg+r (within tile), q=lr
            f32x4 s0 = {0.f,0.f,0.f,0.f}, s1 = {0.f,0.f,0.f,0.f};
            s0 = __builtin_amdgcn_mfma_f32_16x16x32_bf16(kA0, qa[ti][0], s0, 0, 0, 0);
            s0 = __builtin_amdgcn_mfma_f32_16x16x32_bf16(kA1, qa[ti][1], s0, 0, 0, 0);
            s1 = __builtin_amdgcn_mfma_f32_16x16x32_bf16(kB0, qa[ti][0], s1, 0, 0, 0);
            s1 = __builtin_amdgcn_mfma_f32_16x16x32_bf16(kB1, qa[ti][1], s1, 0, 0, 0);
            float p0 = exp2f(s0[0]), p1 = exp2f(s0[1]), p2 = exp2f(s0[2]), p3 = exp2f(s0[3]);
            float r0 = exp2f(s1[0]), r1 = exp2f(s1[1]), r2 = exp2f(s1[2]), r3 = exp2f(s1[3]);
            ssum[ti] += ((p0 + p1) + (p2 + p3)) + ((r0 + r1) + (r2 + r3));
            unsigned a0 = cvt_pk_bf16(p0, p1), a1 = cvt_pk_bf16(p2, p3);
            unsigned b0 = cvt_pk_bf16(r0, r1), b1 = cvt_pk_bf16(r2, r3);
            uint4 pu = make_uint4(a0, a1, b0, b1);
            v8s pb = *(v8s*)&pu;    // B-frag: P^T[pi(g,j)][q=lr]
            #pragma unroll
            for (int dt = 0; dt < 4; ++dt)
                o[ti][dt] = __builtin_amdgcn_mfma_f32_16x16x32_bf16(vf[dt], pb, o[ti][dt], 0, 0, 0);
        }
    }

    __syncthreads();   // all waves done reading K/V; LDS reused for O transpose

    // softmax denominators: each lane has a partial over its 8-key slices; combine
    // the 4 lane-groups sharing q=lr
    float rinv[4];
    #pragma unroll
    for (int ti = 0; ti < 4; ++ti) {
        float v = ssum[ti];
        v += __shfl_xor(v, 16);
        v += __shfl_xor(v, 32);
        rinv[ti] = 1.f / v;
    }

    // per-wave O tile (64q x 64d bf16) -> LDS rows (stride 160B) -> coalesced store
    char* ow = (char*)smem + wave*10240;
    #pragma unroll
    for (int ti = 0; ti < 4; ++ti) {
        #pragma unroll
        for (int dt = 0; dt < 4; ++dt) {
            unsigned d0 = cvt_pk_bf16(o[ti][dt][0]*rinv[ti], o[ti][dt][1]*rinv[ti]);
            unsigned d1 = cvt_pk_bf16(o[ti][dt][2]*rinv[ti], o[ti][dt][3]*rinv[ti]);
            *(uint2*)(ow + (ti*16 + lr)*160 + dt*32 + lg*8) = make_uint2(d0, d1);
        }
    }
    __asm__ volatile("s_waitcnt lgkmcnt(0)" ::: "memory");
    #pragma unroll
    for (int it = 0; it < 8; ++it) {
        int rr = it*8 + (lane >> 3);
        uint4 v = *(const uint4*)(ow + rr*160 + (lane & 7)*16);
        *(uint4*)(O + (size_t)(b*NE + q0 + rr)*DMODEL + h*EMB + (lane & 7)*8) = v;
    }
}

// ---------------- residual + layernorm ----------------
template<int MODE>
__global__ __launch_bounds__(256) void add_ln_kernel(
    const u16* __restrict__ a, const float* __restrict__ r32,
    const u16* __restrict__ r16, const float* __restrict__ g,
    const float* __restrict__ be, u16* __restrict__ out16, float* __restrict__ out32)
{
    const int row = blockIdx.x;
    const int t = threadIdx.x;
    const int lane = t & 63, wave = t >> 6;
    float v[2];
    #pragma unroll
    for (int i = 0; i < 2; ++i) {
        int c = t + i*256;
        size_t idx = (size_t)row * DMODEL + c;
        float av = bf2f_bits(a[idx]);
        float rv = (MODE == 0) ? r32[idx] : bf2f_bits(r16[idx]);
        v[i] = av + rv;
    }
    float s = v[0] + v[1];
    float q = v[0]*v[0] + v[1]*v[1];
    #pragma unroll
    for (int d = 1; d < 64; d <<= 1) { s += __shfl_xor(s, d); q += __shfl_xor(q, d); }
    __shared__ float ssum[4], ssq[4];
    if (lane == 0) { ssum[wave] = s; ssq[wave] = q; }
    __syncthreads();
    s = ssum[0] + ssum[1] + ssum[2] + ssum[3];
    q = ssq[0] + ssq[1] + ssq[2] + ssq[3];
    const float mu = s * (1.f / DMODEL);
    const float var = q * (1.f / DMODEL) - mu * mu;
    const float rs = rsqrtf(var + 1e-5f);
    #pragma unroll
    for (int i = 0; i < 2; ++i) {
        int c = t + i*256;
        size_t idx = (size_t)row * DMODEL + c;
        float ov = (v[i] - mu) * rs * g[c] + be[c];
        if (MODE == 0) out16[idx] = f2bf_bits(ov); else out32[idx] = ov;
    }
}

// ---------------- launcher ----------------

extern "C" void kernel_launch(void* const* d_in, const int* in_sizes, int n_in,
                              void* d_out, int out_size, void* d_ws, size_t ws_size,
                              hipStream_t stream)
{
    const float* x   = (const float*)d_in[0];
    const float* Wq  = (const float*)d_in[1];
    const float* bq  = (const float*)d_in[2];
    const float* Wk  = (const float*)d_in[3];
    const float* bk  = (const float*)d_in[4];
    const float* Wv  = (const float*)d_in[5];
    const float* bv  = (const float*)d_in[6];
    const float* W1  = (const float*)d_in[7];
    const float* bf1 = (const float*)d_in[8];
    const float* W2  = (const float*)d_in[9];
    const float* bf2 = (const float*)d_in[10];
    const float* g1  = (const float*)d_in[11];
    const float* be1 = (const float*)d_in[12];
    const float* g2  = (const float*)d_in[13];
    const float* be2 = (const float*)d_in[14];

    char* ws = (char*)d_ws;
    const size_t MB = 1ull << 20;
    const size_t KB = 1024;
    u16* xb    = (u16*)(ws + 0);          // x bf16 (dead after QKV GEMM)
    u16* attnb = (u16*)(ws + 0);          // attention output (aliases xb)
    u16* qb    = (u16*)(ws + 16*MB);      // q (dead after attn)
    u16* f1    = (u16*)(ws + 16*MB);      // ff hidden (aliases qb)
    u16* kb    = (u16*)(ws + 32*MB);      // k (dead after attn)
    u16* ffb   = (u16*)(ws + 32*MB);      // ff output (aliases kb)
    u16* vT    = (u16*)(ws + 48*MB);      // v transposed [b][h][d][ne]
    u16* hb    = (u16*)(ws + 64*MB);      // h = LN1 output
    u16* WqkvT = (u16*)(ws + 80*MB);                 // [1536][512]
    u16* W1T   = (u16*)(ws + 80*MB + 1536*KB);       // [256][512]
    u16* W2T   = (u16*)(ws + 80*MB + 1792*KB);       // [512][256]
    (void)ws_size; (void)in_sizes; (void)n_in; (void)out_size;

    cvt_x_kernel<<<8192, 256, 0, stream>>>(x, xb, MTOK*DMODEL/4);
    cvt_w_kernel<<<4096, 256, 0, stream>>>(Wq, Wk, Wv, W1, W2, WqkvT, W1T, W2T);

    gemm_kernel<3, 512><<<1536, 256, 0, stream>>>(xb, WqkvT, bq, bk, bv, qb, kb, vT, 1536, 12);

    attn_kernel<<<256, 512, 132096, stream>>>(qb, kb, vT, attnb);

    add_ln_kernel<0><<<MTOK, 256, 0, stream>>>(attnb, x, nullptr, g1, be1, hb, nullptr);

    gemm_kernel<2, 512><<<256, 256, 0, stream>>>(hb, W1T, bf1, bf1, bf1, f1, f1, f1, 256, 2);
    gemm_kernel<0, 256><<<512, 256, 0, stream>>>(f1, W2T, bf2, bf2, bf2, ffb, ffb, ffb, 512, 4);

    add_ln_kernel<1><<<MTOK, 256, 0, stream>>>(ffb, nullptr, hb, g2, be2, nullptr, (float*)d_out);
}

// Round 7
// 142.457 us; speedup vs baseline: 1.1355x; 1.1355x over previous
//
#include <hip/hip_runtime.h>

#define BS 32
#define NE 512
#define DMODEL 512
#define HEADS 8
#define EMB 64
#define FFH 256
#define MTOK (BS*NE)   // 16384

typedef unsigned short u16;
typedef short v8s __attribute__((ext_vector_type(8)));
typedef float f32x4 __attribute__((ext_vector_type(4)));
typedef u16 u16x4 __attribute__((ext_vector_type(4)));

#define GLOAD16(G, L) \
  __builtin_amdgcn_global_load_lds((const __attribute__((address_space(1))) unsigned int*)(G), \
      (__attribute__((address_space(3))) unsigned int*)(L), 16, 0, 0)

static __device__ __forceinline__ unsigned cvt_pk_bf16(float lo, float hi) {
    unsigned r;
    asm("v_cvt_pk_bf16_f32 %0, %1, %2" : "=v"(r) : "v"(lo), "v"(hi));
    return r;
}

static __device__ __forceinline__ u16 f2bf_bits(float f) {
    unsigned u = __float_as_uint(f);
    u += 0x7fffu + ((u >> 16) & 1u);   // round-to-nearest-even
    return (u16)(u >> 16);
}
static __device__ __forceinline__ float bf2f_bits(u16 h) {
    return __uint_as_float(((unsigned)h) << 16);
}

// ---------------- conversion kernels ----------------

__global__ __launch_bounds__(256) void cvt_x_kernel(const float* __restrict__ x,
                                                    u16* __restrict__ xb, int n4) {
    int i = blockIdx.x * 256 + threadIdx.x;
    if (i >= n4) return;
    float4 v = ((const float4*)x)[i];
    u16x4 o = { f2bf_bits(v.x), f2bf_bits(v.y), f2bf_bits(v.z), f2bf_bits(v.w) };
    ((u16x4*)xb)[i] = o;
}

// all 5 weights -> transposed bf16 in one kernel.
__global__ __launch_bounds__(256) void cvt_w_kernel(
    const float* __restrict__ Wq, const float* __restrict__ Wk, const float* __restrict__ Wv,
    const float* __restrict__ W1, const float* __restrict__ W2,
    u16* __restrict__ WqkvT, u16* __restrict__ W1T, u16* __restrict__ W2T)
{
    int idx = blockIdx.x * 256 + threadIdx.x;   // 0 .. 1048575
    if (idx < 786432) {
        int w = idx >> 18, rem = idx & 262143;
        int k = rem >> 9, n = rem & 511;
        const float* src = (w == 0) ? Wq : (w == 1) ? Wk : Wv;
        WqkvT[(size_t)(w*512 + n)*512 + k] = f2bf_bits(src[rem]);
    } else if (idx < 917504) {
        int rem = idx - 786432;        // W1: [512][256]
        int k = rem >> 8, n = rem & 255;
        W1T[n*512 + k] = f2bf_bits(W1[rem]);
    } else if (idx < 1048576) {
        int rem = idx - 917504;        // W2: [256][512]
        int k = rem >> 9, n = rem & 511;
        W2T[n*256 + k] = f2bf_bits(W2[rem]);
    }
}

// ---------------- GEMM: C = A(MxKC) @ BT(NxKC)^T + bias ----------------
// 128x128 tile, 4 waves, BK=64, double-buffered LDS, one barrier per K-step.
// Epilogues are VECTORIZED (16x uint2 stores/thread, not 64x 2B scalar):
//  EPI 0: swapped acc (C^T = mfma(B,A)) -> row-major store, lane's 4 acc = 4 consecutive cols
//  EPI 2: same + relu
//  EPI 4: QK part of fused QKV (swapped; sel by col block; Q pre-scaled)
//  EPI 5: V part (normal acc: lane's 4 acc = 4 consecutive tokens -> vT row-packed)
template<int EPI, int KC>
__global__ __launch_bounds__(256, 2) void gemm_kernel(
    const u16* __restrict__ A, const u16* __restrict__ BT,
    const float* __restrict__ bsQ, const float* __restrict__ bsK, const float* __restrict__ bsV,
    u16* __restrict__ oQ, u16* __restrict__ oK, u16* __restrict__ oVT,
    int N, int NC, int colBase)
{
    __shared__ u16 Ab[2][128*64];
    __shared__ u16 Bb[2][128*64];
    const int tid = threadIdx.x;
    const int wave = tid >> 6, lane = tid & 63;
    const int lr = lane & 15, lg = lane >> 4, lr7 = lr & 7;
    const int id = blockIdx.x;
    const int rr = id & 7, qq = id >> 3;
    const int gk = qq / NC, colBlk = qq - gk*NC;
    const int rowBlk = gk*8 + rr;
    const int aRow0 = rowBlk*128, bRow0 = colBase + colBlk*128;
    const int wlo = (wave >> 1)*64, wco = (wave & 1)*64;
    const int srow = tid >> 3, schunk = tid & 7;
    const int soff = ((schunk ^ (srow & 7)) << 3);

    auto stage = [&](int bsel, int k0) {
        #pragma unroll
        for (int i = 0; i < 4; ++i) {
            int row = i*32 + srow;
            GLOAD16(A  + (size_t)(aRow0 + row)*KC + k0 + soff, (char*)&Ab[bsel][0] + i*4096 + wave*1024);
            GLOAD16(BT + (size_t)(bRow0 + row)*KC + k0 + soff, (char*)&Bb[bsel][0] + i*4096 + wave*1024);
        }
    };

    stage(0, 0);

    f32x4 acc[4][4] = {};
    constexpr int NT = KC / 64;
    #pragma unroll
    for (int t = 0; t < NT; ++t) {
        const int cur = t & 1;
        asm volatile("s_waitcnt vmcnt(0)" ::: "memory");
        __builtin_amdgcn_s_barrier();
        if (t + 1 < NT) stage(cur ^ 1, (t + 1) * 64);
        #pragma unroll
        for (int kk = 0; kk < 2; ++kk) {
            v8s af[4], bf[4];
            #pragma unroll
            for (int i = 0; i < 4; ++i) {
                af[i] = *(const v8s*)((const char*)&Ab[cur][0] + (wlo + i*16 + lr)*128 + ((((kk<<2)|lg) ^ lr7) << 4));
                bf[i] = *(const v8s*)((const char*)&Bb[cur][0] + (wco + i*16 + lr)*128 + ((((kk<<2)|lg) ^ lr7) << 4));
            }
            #pragma unroll
            for (int i = 0; i < 4; ++i)
                #pragma unroll
                for (int j = 0; j < 4; ++j) {
                    if (EPI == 5)
                        acc[i][j] = __builtin_amdgcn_mfma_f32_16x16x32_bf16(af[i], bf[j], acc[i][j], 0, 0, 0);
                    else   // swapped: acc holds C^T fragment (col<->row)
                        acc[i][j] = __builtin_amdgcn_mfma_f32_16x16x32_bf16(bf[j], af[i], acc[i][j], 0, 0, 0);
                }
        }
    }

    if (EPI == 5) {
        // normal acc: col=lr (d-col), row=4lg+r (token) -> pack 4 tokens into vT row
        #pragma unroll
        for (int j = 0; j < 4; ++j) {
            int col = (bRow0 & 511) + wco + j*16 + lr;
            float bv = bsV[col];
            int hh = col >> 6, d = col & 63;
            #pragma unroll
            for (int i = 0; i < 4; ++i) {
                int t0 = aRow0 + wlo + i*16 + lg*4;
                int bb = t0 >> 9, tr = t0 & 511;
                unsigned lo = cvt_pk_bf16(acc[i][j][0] + bv, acc[i][j][1] + bv);
                unsigned hi = cvt_pk_bf16(acc[i][j][2] + bv, acc[i][j][3] + bv);
                *(uint2*)(oVT + ((size_t)((bb*HEADS + hh)*EMB + d))*NE + tr) = make_uint2(lo, hi);
            }
        }
    } else {
        // swapped acc: row=...+lr, cols=...+4lg+{0..3} -> one uint2 per (i,j)
        const int sel = (EPI == 4) ? (bRow0 >> 9) : 0;
        u16* dst = (EPI == 4) ? (sel ? oK : oQ) : oQ;
        const float* bias = (EPI == 4) ? (sel ? bsK : bsQ) : bsQ;
        const int cb = (EPI == 4) ? (bRow0 & 511) : bRow0;
        const int ldc = (EPI == 4) ? DMODEL : N;
        #pragma unroll
        for (int j = 0; j < 4; ++j) {
            int col0 = cb + wco + j*16 + lg*4;
            float4 b4 = *(const float4*)&bias[col0];
            #pragma unroll
            for (int i = 0; i < 4; ++i) {
                int row = aRow0 + wlo + i*16 + lr;
                float v0 = acc[i][j][0] + b4.x, v1 = acc[i][j][1] + b4.y;
                float v2 = acc[i][j][2] + b4.z, v3 = acc[i][j][3] + b4.w;
                if (EPI == 2) { v0 = fmaxf(v0, 0.f); v1 = fmaxf(v1, 0.f);
                                v2 = fmaxf(v2, 0.f); v3 = fmaxf(v3, 0.f); }
                if (EPI == 4 && sel == 0) {
                    const float SCL = 0.18033688011112042f;   // 0.125*log2(e)
                    v0 *= SCL; v1 *= SCL; v2 *= SCL; v3 *= SCL;
                }
                *(uint2*)(dst + (size_t)row*ldc + col0)
                    = make_uint2(cvt_pk_bf16(v0, v1), cvt_pk_bf16(v2, v3));
            }
        }
    }
}

// ---------------- attention (streaming, swapped-operand, permuted-key PV) ----------------
__global__ __launch_bounds__(512, 2) void attn_kernel(
    const u16* __restrict__ Q, const u16* __restrict__ Kb,
    const u16* __restrict__ VT, u16* __restrict__ O)
{
    extern __shared__ char smem[];   // [0,64K) K swz; [64K, 64K+66560) V^T padded
    const int b = blockIdx.x >> 3, h = blockIdx.x & 7;
    const int tid = threadIdx.x, wave = tid >> 6, lane = tid & 63;
    const int lr = lane & 15, lg = lane >> 4, lr7 = lr & 7;

    // stage K rows (128B, 8x16B chunks, chunk ^= row&7), pre-swizzled source
    const int srow = tid >> 3, schunk = tid & 7;
    const int soff = ((schunk ^ (srow & 7)) << 3);
    #pragma unroll
    for (int i = 0; i < 8; ++i)
        GLOAD16(Kb + (size_t)(b*NE + i*64 + srow)*DMODEL + h*EMB + soff,
                (char*)smem + i*8192 + wave*1024);
    // stage V^T rows: 1024B data per row, stride 1040B, linear (no swizzle)
    #pragma unroll
    for (int i = 0; i < 8; ++i) {
        int row = i*8 + wave;
        GLOAD16(VT + (size_t)((b*HEADS + h)*EMB + row)*NE + lane*8,
                (char*)smem + 65536 + row*1040);
    }

    // Q fragments direct from global (L2-resident); Q pre-scaled by 0.125*log2e
    const int q0 = wave*64;
    v8s qa[4][2];
    #pragma unroll
    for (int ti = 0; ti < 4; ++ti) {
        const u16* qr = Q + (size_t)(b*NE + q0 + ti*16 + lr)*DMODEL + h*EMB;
        qa[ti][0] = *(const v8s*)(qr + lg*8);
        qa[ti][1] = *(const v8s*)(qr + 32 + lg*8);
    }
    __syncthreads();

    f32x4 o[4][4] = {};
    float ssum[4] = {0.f, 0.f, 0.f, 0.f};

    #pragma unroll 1
    for (int c = 0; c < 16; ++c) {
        const char* kr0 = (const char*)smem + ((2*c  )*16 + lr)*128;
        const char* kr1 = (const char*)smem + ((2*c+1)*16 + lr)*128;
        v8s kA0 = *(const v8s*)(kr0 + ((lg ^ lr7) << 4));
        v8s kA1 = *(const v8s*)(kr0 + (((4|lg) ^ lr7) << 4));
        v8s kB0 = *(const v8s*)(kr1 + ((lg ^ lr7) << 4));
        v8s kB1 = *(const v8s*)(kr1 + (((4|lg) ^ lr7) << 4));
        v8s vf[4];
        #pragma unroll
        for (int dt = 0; dt < 4; ++dt) {
            const char* vr = (const char*)smem + 65536 + (dt*16 + lr)*1040 + c*64 + lg*8;
            uint2 lo = *(const uint2*)(vr);
            uint2 hi = *(const uint2*)(vr + 32);
            uint4 u = make_uint4(lo.x, lo.y, hi.x, hi.y);
            vf[dt] = *(v8s*)&u;
        }
        #pragma unroll
        for (int ti = 0; ti < 4; ++ti) {
            f32x4 s0 = {0.f,0.f,0.f,0.f}, s1 = {0.f,0.f,0.f,0.f};
            s0 = __builtin_amdgcn_mfma_f32_16x16x32_bf16(kA0, qa[ti][0], s0, 0, 0, 0);
            s0 = __builtin_amdgcn_mfma_f32_16x16x32_bf16(kA1, qa[ti][1], s0, 0, 0, 0);
            s1 = __builtin_amdgcn_mfma_f32_16x16x32_bf16(kB0, qa[ti][0], s1, 0, 0, 0);
            s1 = __builtin_amdgcn_mfma_f32_16x16x32_bf16(kB1, qa[ti][1], s1, 0, 0, 0);
            float p0 = exp2f(s0[0]), p1 = exp2f(s0[1]), p2 = exp2f(s0[2]), p3 = exp2f(s0[3]);
            float r0 = exp2f(s1[0]), r1 = exp2f(s1[1]), r2 = exp2f(s1[2]), r3 = exp2f(s1[3]);
            ssum[ti] += ((p0 + p1) + (p2 + p3)) + ((r0 + r1) + (r2 + r3));
            unsigned a0 = cvt_pk_bf16(p0, p1), a1 = cvt_pk_bf16(p2, p3);
            unsigned b0 = cvt_pk_bf16(r0, r1), b1 = cvt_pk_bf16(r2, r3);
            uint4 pu = make_uint4(a0, a1, b0, b1);
            v8s pb = *(v8s*)&pu;
            #pragma unroll
            for (int dt = 0; dt < 4; ++dt)
                o[ti][dt] = __builtin_amdgcn_mfma_f32_16x16x32_bf16(vf[dt], pb, o[ti][dt], 0, 0, 0);
        }
    }

    __syncthreads();

    float rinv[4];
    #pragma unroll
    for (int ti = 0; ti < 4; ++ti) {
        float v = ssum[ti];
        v += __shfl_xor(v, 16);
        v += __shfl_xor(v, 32);
        rinv[ti] = 1.f / v;
    }

    char* ow = (char*)smem + wave*10240;
    #pragma unroll
    for (int ti = 0; ti < 4; ++ti) {
        #pragma unroll
        for (int dt = 0; dt < 4; ++dt) {
            unsigned d0 = cvt_pk_bf16(o[ti][dt][0]*rinv[ti], o[ti][dt][1]*rinv[ti]);
            unsigned d1 = cvt_pk_bf16(o[ti][dt][2]*rinv[ti], o[ti][dt][3]*rinv[ti]);
            *(uint2*)(ow + (ti*16 + lr)*160 + dt*32 + lg*8) = make_uint2(d0, d1);
        }
    }
    __asm__ volatile("s_waitcnt lgkmcnt(0)" ::: "memory");
    #pragma unroll
    for (int it = 0; it < 8; ++it) {
        int rr2 = it*8 + (lane >> 3);
        uint4 v = *(const uint4*)(ow + rr2*160 + (lane & 7)*16);
        *(uint4*)(O + (size_t)(b*NE + q0 + rr2)*DMODEL + h*EMB + (lane & 7)*8) = v;
    }
}

// ---------------- residual + layernorm ----------------
template<int MODE>
__global__ __launch_bounds__(256) void add_ln_kernel(
    const u16* __restrict__ a, const float* __restrict__ r32,
    const u16* __restrict__ r16, const float* __restrict__ g,
    const float* __restrict__ be, u16* __restrict__ out16, float* __restrict__ out32)
{
    const int row = blockIdx.x;
    const int t = threadIdx.x;
    const int lane = t & 63, wave = t >> 6;
    float v[2];
    #pragma unroll
    for (int i = 0; i < 2; ++i) {
        int c = t + i*256;
        size_t idx = (size_t)row * DMODEL + c;
        float av = bf2f_bits(a[idx]);
        float rv = (MODE == 0) ? r32[idx] : bf2f_bits(r16[idx]);
        v[i] = av + rv;
    }
    float s = v[0] + v[1];
    float q = v[0]*v[0] + v[1]*v[1];
    #pragma unroll
    for (int d = 1; d < 64; d <<= 1) { s += __shfl_xor(s, d); q += __shfl_xor(q, d); }
    __shared__ float ssum[4], ssq[4];
    if (lane == 0) { ssum[wave] = s; ssq[wave] = q; }
    __syncthreads();
    s = ssum[0] + ssum[1] + ssum[2] + ssum[3];
    q = ssq[0] + ssq[1] + ssq[2] + ssq[3];
    const float mu = s * (1.f / DMODEL);
    const float var = q * (1.f / DMODEL) - mu * mu;
    const float rs = rsqrtf(var + 1e-5f);
    #pragma unroll
    for (int i = 0; i < 2; ++i) {
        int c = t + i*256;
        size_t idx = (size_t)row * DMODEL + c;
        float ov = (v[i] - mu) * rs * g[c] + be[c];
        if (MODE == 0) out16[idx] = f2bf_bits(ov); else out32[idx] = ov;
    }
}

// ---------------- launcher ----------------

extern "C" void kernel_launch(void* const* d_in, const int* in_sizes, int n_in,
                              void* d_out, int out_size, void* d_ws, size_t ws_size,
                              hipStream_t stream)
{
    const float* x   = (const float*)d_in[0];
    const float* Wq  = (const float*)d_in[1];
    const float* bq  = (const float*)d_in[2];
    const float* Wk  = (const float*)d_in[3];
    const float* bk  = (const float*)d_in[4];
    const float* Wv  = (const float*)d_in[5];
    const float* bv  = (const float*)d_in[6];
    const float* W1  = (const float*)d_in[7];
    const float* bf1 = (const float*)d_in[8];
    const float* W2  = (const float*)d_in[9];
    const float* bf2 = (const float*)d_in[10];
    const float* g1  = (const float*)d_in[11];
    const float* be1 = (const float*)d_in[12];
    const float* g2  = (const float*)d_in[13];
    const float* be2 = (const float*)d_in[14];

    char* ws = (char*)d_ws;
    const size_t MB = 1ull << 20;
    const size_t KB = 1024;
    u16* xb    = (u16*)(ws + 0);          // x bf16 (dead after QKV GEMM)
    u16* attnb = (u16*)(ws + 0);          // attention output (aliases xb)
    u16* qb    = (u16*)(ws + 16*MB);      // q (dead after attn)
    u16* f1    = (u16*)(ws + 16*MB);      // ff hidden (aliases qb)
    u16* kb    = (u16*)(ws + 32*MB);      // k (dead after attn)
    u16* ffb   = (u16*)(ws + 32*MB);      // ff output (aliases kb)
    u16* vT    = (u16*)(ws + 48*MB);      // v transposed [b][h][d][ne]
    u16* hb    = (u16*)(ws + 64*MB);      // h = LN1 output
    u16* WqkvT = (u16*)(ws + 80*MB);                 // [1536][512]
    u16* W1T   = (u16*)(ws + 80*MB + 1536*KB);       // [256][512]
    u16* W2T   = (u16*)(ws + 80*MB + 1792*KB);       // [512][256]
    (void)ws_size; (void)in_sizes; (void)n_in; (void)out_size;

    cvt_x_kernel<<<8192, 256, 0, stream>>>(x, xb, MTOK*DMODEL/4);
    cvt_w_kernel<<<4096, 256, 0, stream>>>(Wq, Wk, Wv, W1, W2, WqkvT, W1T, W2T);

    // fused QKV, split by output orientation: QK (swapped acc) + V (normal acc)
    gemm_kernel<4, 512><<<1024, 256, 0, stream>>>(xb, WqkvT, bq, bk, bv, qb, kb, vT, 1536, 8, 0);
    gemm_kernel<5, 512><<<512,  256, 0, stream>>>(xb, WqkvT, bq, bk, bv, qb, kb, vT, 1536, 4, 1024);

    attn_kernel<<<256, 512, 132096, stream>>>(qb, kb, vT, attnb);

    add_ln_kernel<0><<<MTOK, 256, 0, stream>>>(attnb, x, nullptr, g1, be1, hb, nullptr);

    gemm_kernel<2, 512><<<256, 256, 0, stream>>>(hb, W1T, bf1, bf1, bf1, f1, f1, f1, 256, 2, 0);
    gemm_kernel<0, 256><<<512, 256, 0, stream>>>(f1, W2T, bf2, bf2, bf2, ffb, ffb, ffb, 512, 4, 0);

    add_ln_kernel<1><<<MTOK, 256, 0, stream>>>(ffb, nullptr, hb, g2, be2, nullptr, (float*)d_out);
}